// Round 1
// baseline (3304.961 us; speedup 1.0000x reference)
//
#include <hip/hip_runtime.h>

// LSTMencoder: 2-layer biLSTM, B=256, T=2048, H=32 (4H=128 gates), in=32/64.
//
// Path A (needs ws >= 671 MB): precompute input-side gate preactivations
//   xg[d][t][b][128] with a parallel GEMM (incl. both biases), then a slim
//   serial recurrence kernel (512 waves) that only does the h-side dot
//   (64 FMAs, split into 8 independent chains for ILP), nonlinearities and
//   the readlane h-broadcast. Per-lane state ~90 floats -> no scratch spill
//   (the old fused kernel spilled: VGPR_Count=104 << required ~200+).
// Path B (fallback): the previous harness-verified fused kernel, unchanged.

#define T_LEN 2048
#define BATCH 256
#define HID   32

__device__ __forceinline__ float frcp(float x) { return __builtin_amdgcn_rcpf(x); }
__device__ __forceinline__ float rdlane(float v, int k) {
    return __int_as_float(__builtin_amdgcn_readlane(__float_as_int(v), k));
}

template<int N>
__device__ __forceinline__ void load_row(float* dst, const float* __restrict__ src) {
#pragma unroll
    for (int i = 0; i < N / 4; ++i) {
        float4 v = reinterpret_cast<const float4*>(src)[i];
        dst[4*i+0] = v.x; dst[4*i+1] = v.y; dst[4*i+2] = v.z; dst[4*i+3] = v.w;
    }
}

// ===================== Path A: xg precompute GEMM =====================
// LAYER 0: x[t][f] = f<16 ? OS[b][t][f] : IS[b][T-1-t][f-16]  (F=32)
// LAYER 1: x[t][f] = h1[t][b][f]                               (F=64)
// xg[((d*T + t)*B + b)*128 + g] = bih[d][g]+bhh[d][g] + sum_f x[f]*Wih[d][g][f]
template<int LAYER>
__global__ __launch_bounds__(256) void xg_gemm(
        const float* __restrict__ OS, const float* __restrict__ IS,
        const float* __restrict__ h1,
        const float* __restrict__ Wih, const float* __restrict__ bih,
        const float* __restrict__ bhh, float* __restrict__ xg)
{
    constexpr int F  = (LAYER == 0) ? 32 : 64;
    constexpr int TT = 16;                      // timesteps per block
    __shared__ float xs[TT][F];
    const int tid = threadIdx.x;
    const int d   = tid >> 7;                   // 0..1
    const int g   = tid & 127;                  // 0..127
    const int t0  = blockIdx.x * TT;
    const int b   = blockIdx.y;

    // stage x tile into LDS (coalesced)
    if (LAYER == 0) {
#pragma unroll
        for (int rep = 0; rep < 2; ++rep) {
            int flat = rep * 256 + tid;         // 0..511
            int tt = flat >> 5, f = flat & 31;
            int t = t0 + tt;
            float v = (f < 16)
                ? OS[((size_t)b * T_LEN + t) * 16 + f]
                : IS[((size_t)b * T_LEN + (T_LEN - 1 - t)) * 16 + (f - 16)];
            xs[tt][f] = v;
        }
    } else {
#pragma unroll
        for (int rep = 0; rep < 4; ++rep) {
            int flat = rep * 256 + tid;         // 0..1023
            int tt = flat >> 6, f = flat & 63;
            xs[tt][f] = h1[((size_t)(t0 + tt) * BATCH + b) * 64 + f];
        }
    }

    // per-thread weight row (L2-resident: only 32KB total per dir-pair)
    float w[F];
    load_row<F>(w, Wih + ((size_t)d * 128 + g) * F);
    const float bias = bih[d * 128 + g] + bhh[d * 128 + g];
    __syncthreads();

#pragma unroll
    for (int tt = 0; tt < TT; ++tt) {
        float a0 = bias, a1 = 0.f, a2 = 0.f, a3 = 0.f;
#pragma unroll
        for (int j = 0; j < F / 4; ++j) {
            float4 x = reinterpret_cast<const float4*>(xs[tt])[j];
            a0 = fmaf(x.x, w[4*j+0], a0);
            a1 = fmaf(x.y, w[4*j+1], a1);
            a2 = fmaf(x.z, w[4*j+2], a2);
            a3 = fmaf(x.w, w[4*j+3], a3);
        }
        xg[(((size_t)d * T_LEN + (t0 + tt)) * BATCH + b) * 128 + g] = (a0 + a1) + (a2 + a3);
    }
}

// ===================== Path A: slim serial recurrence =====================
// One wave per (b, dir) chain. Lane l owns gates gA=l (i|f), gB=64+l (g|o).
// Reads xg (biases already folded in). Writes h1 (LAYER 0) or out (LAYER 1).
template<int LAYER>
__global__ __launch_bounds__(64, 1) void lstm_rec_xg(
        const float* __restrict__ xg, const float* __restrict__ Whh,
        float* __restrict__ outp)
{
    const int l   = threadIdx.x;     // 0..63
    const int b   = blockIdx.x;      // 0..255
    const int d   = blockIdx.y;      // 0 fwd, 1 bwd
    const int gA  = l;
    const int gB  = 64 + l;
    const bool lo = (l < HID);

    float whh_a[HID], whh_b[HID];
    load_row<HID>(whh_a, Whh + ((size_t)d * 128 + gA) * HID);
    load_row<HID>(whh_b, Whh + ((size_t)d * 128 + gB) * HID);

    float h[HID];                    // wave-uniform (readlane -> SGPR)
#pragma unroll
    for (int k = 0; k < HID; ++k) h[k] = 0.f;
    float c = 0.f;

    const float* xgb = xg + ((size_t)d * T_LEN * BATCH + b) * 128;
    auto xg_addr = [&](int tl) -> const float* {
        int te = d ? (T_LEN - 1 - tl) : tl;
        return xgb + (size_t)te * (BATCH * 128);
    };

    constexpr int PF = 8;            // prefetch depth (ring; statically indexed)
    float ra[PF], rb[PF];
#pragma unroll
    for (int u = 0; u < PF; ++u) {
        const float* p = xg_addr(u);
        ra[u] = p[gA];
        rb[u] = p[gB];
    }

#pragma unroll 1
    for (int tb = 0; tb < T_LEN; tb += PF) {
#pragma unroll
        for (int u = 0; u < PF; ++u) {
            const int tl = tb + u;
            const int te = d ? (T_LEN - 1 - tl) : tl;
            const float xa = ra[u], xb = rb[u];
            // prefetch slot for tl+PF (clamped; tail values unused)
            int tp = tl + PF; if (tp > T_LEN - 1) tp = T_LEN - 1;
            const float* p = xg_addr(tp);
            ra[u] = p[gA];
            rb[u] = p[gB];
            // recurrent dot: 8 independent FMA chains of length 8
            float a0 = xa, a1 = 0.f, a2 = 0.f, a3 = 0.f;
            float b0 = xb, b1 = 0.f, b2 = 0.f, b3 = 0.f;
#pragma unroll
            for (int k = 0; k < 8; ++k) {
                a0 = fmaf(h[k],      whh_a[k],      a0);
                a1 = fmaf(h[k + 8],  whh_a[k + 8],  a1);
                a2 = fmaf(h[k + 16], whh_a[k + 16], a2);
                a3 = fmaf(h[k + 24], whh_a[k + 24], a3);
                b0 = fmaf(h[k],      whh_b[k],      b0);
                b1 = fmaf(h[k + 8],  whh_b[k + 8],  b1);
                b2 = fmaf(h[k + 16], whh_b[k + 16], b2);
                b3 = fmaf(h[k + 24], whh_b[k + 24], b3);
            }
            const float accA = (a0 + a1) + (a2 + a3);
            const float accB = (b0 + b1) + (b2 + b3);
            // accA -> sigmoid (i|f); accB -> tanh (g) or sigmoid (o)
            float sA = frcp(1.f + __expf(-accA));
            float argB = lo ? (-2.f * accB) : (-accB);
            float rB = frcp(1.f + __expf(argB));
            float sB = lo ? fmaf(2.f, rB, -1.f) : rB;
            float sf = __shfl(sA, (l + 32) & 63);
            float so = __shfl(sB, (l + 32) & 63);
            c = fmaf(sf, c, sA * sB);
            float tc = fmaf(2.f, frcp(1.f + __expf(-2.f * c)), -1.f);
            float hj = so * tc;
            if (lo) {
                if constexpr (LAYER == 0)
                    outp[((size_t)te * BATCH + b) * 64 + d * HID + l] = hj;
                else
                    outp[((size_t)b * T_LEN + te) * 64 + d * HID + l] = hj;
            }
#pragma unroll
            for (int k = 0; k < HID; ++k) h[k] = rdlane(hj, k);
        }
    }
}

// ===================== Path B: previous verified fused kernel =====================
template<int LAYER>
__global__ __launch_bounds__(64, 1) void lstm_rec(
        const float* __restrict__ OS, const float* __restrict__ IS,
        const float* __restrict__ Wih, const float* __restrict__ Whh,
        const float* __restrict__ bih, const float* __restrict__ bhh,
        const float* __restrict__ h1in, float* __restrict__ outp)
{
    constexpr int F = (LAYER == 0) ? 32 : 64;
    const int l   = threadIdx.x;
    const int b   = blockIdx.x;
    const int dir = blockIdx.y;
    const int gA  = l;
    const int gB  = 64 + l;

    float wih_a[F], wih_b[F], whh_a[HID], whh_b[HID];
    load_row<F>(wih_a, Wih + ((size_t)dir * 128 + gA) * F);
    load_row<F>(wih_b, Wih + ((size_t)dir * 128 + gB) * F);
    load_row<HID>(whh_a, Whh + ((size_t)dir * 128 + gA) * HID);
    load_row<HID>(whh_b, Whh + ((size_t)dir * 128 + gB) * HID);
    const float biasA = bih[dir * 128 + gA] + bhh[dir * 128 + gA];
    const float biasB = bih[dir * 128 + gB] + bhh[dir * 128 + gB];

    float h[HID];
#pragma unroll
    for (int k = 0; k < HID; ++k) h[k] = 0.f;
    float c = 0.f;
    const bool lo = (l < HID);

    float4 X0[F / 4], X1[F / 4];

    auto load_x = [&](float4* X, int tl) {
        const int te = dir ? (T_LEN - 1 - tl) : tl;
        if constexpr (LAYER == 0) {
            const float4* p0 = reinterpret_cast<const float4*>(OS + ((size_t)b * T_LEN + te) * 16);
            const float4* p1 = reinterpret_cast<const float4*>(IS + ((size_t)b * T_LEN + (T_LEN - 1 - te)) * 16);
#pragma unroll
            for (int i = 0; i < 4; ++i) X[i] = p0[i];
#pragma unroll
            for (int i = 0; i < 4; ++i) X[4 + i] = p1[i];
        } else {
            const float4* p = reinterpret_cast<const float4*>(h1in + ((size_t)te * BATCH + b) * 64);
#pragma unroll
            for (int i = 0; i < F / 4; ++i) X[i] = p[i];
        }
    };

    auto step = [&](int tl, const float4* X) {
        const int te = dir ? (T_LEN - 1 - tl) : tl;
        float accA = biasA, accB = biasB;
#pragma unroll
        for (int i = 0; i < F / 4; ++i) {
            accA = fmaf(X[i].x, wih_a[4*i+0], accA);
            accA = fmaf(X[i].y, wih_a[4*i+1], accA);
            accA = fmaf(X[i].z, wih_a[4*i+2], accA);
            accA = fmaf(X[i].w, wih_a[4*i+3], accA);
            accB = fmaf(X[i].x, wih_b[4*i+0], accB);
            accB = fmaf(X[i].y, wih_b[4*i+1], accB);
            accB = fmaf(X[i].z, wih_b[4*i+2], accB);
            accB = fmaf(X[i].w, wih_b[4*i+3], accB);
        }
#pragma unroll
        for (int k = 0; k < HID; ++k) {
            accA = fmaf(h[k], whh_a[k], accA);
            accB = fmaf(h[k], whh_b[k], accB);
        }
        float sA = frcp(1.f + __expf(-accA));
        float argB = lo ? (-2.f * accB) : (-accB);
        float rB = frcp(1.f + __expf(argB));
        float sB = lo ? fmaf(2.f, rB, -1.f) : rB;
        float sf = __shfl(sA, (l + 32) & 63);
        float so = __shfl(sB, (l + 32) & 63);
        c = fmaf(sf, c, sA * sB);
        float tc = fmaf(2.f, frcp(1.f + __expf(-2.f * c)), -1.f);
        float hj = so * tc;
        if (lo) {
            if constexpr (LAYER == 0)
                outp[((size_t)te * BATCH + b) * 64 + dir * HID + l] = hj;
            else
                outp[((size_t)b * T_LEN + te) * 64 + dir * HID + l] = hj;
        }
#pragma unroll
        for (int k = 0; k < HID; ++k) h[k] = rdlane(hj, k);
    };

    load_x(X0, 0);
#pragma unroll 1
    for (int tt = 0; tt < T_LEN; tt += 2) {
        load_x(X1, tt + 1);
        step(tt, X0);
        int nx = tt + 2; if (nx > T_LEN - 1) nx = T_LEN - 1;
        load_x(X0, nx);
        step(tt + 1, X1);
    }
}

extern "C" void kernel_launch(void* const* d_in, const int* in_sizes, int n_in,
                              void* d_out, int out_size, void* d_ws, size_t ws_size,
                              hipStream_t stream) {
    const float* OS    = (const float*)d_in[0];
    const float* IS    = (const float*)d_in[1];
    const float* W_ih0 = (const float*)d_in[2];
    const float* W_hh0 = (const float*)d_in[3];
    const float* b_ih0 = (const float*)d_in[4];
    const float* b_hh0 = (const float*)d_in[5];
    const float* W_ih1 = (const float*)d_in[6];
    const float* W_hh1 = (const float*)d_in[7];
    const float* b_ih1 = (const float*)d_in[8];
    const float* b_hh1 = (const float*)d_in[9];
    float* out = (float*)d_out;

    const size_t XG_BYTES = (size_t)2 * T_LEN * BATCH * 128 * sizeof(float); // 536,870,912
    const size_t H1_BYTES = (size_t)T_LEN * BATCH * 64 * sizeof(float);      // 134,217,728

    if (ws_size >= XG_BYTES + H1_BYTES) {
        // -------- Path A --------
        float* xg = (float*)d_ws;
        float* h1 = (float*)((char*)d_ws + XG_BYTES);
        dim3 gg(T_LEN / 16, BATCH), gb(256);
        dim3 rg(BATCH, 2), rb(64);
        hipLaunchKernelGGL((xg_gemm<0>), gg, gb, 0, stream,
                           OS, IS, (const float*)nullptr, W_ih0, b_ih0, b_hh0, xg);
        hipLaunchKernelGGL((lstm_rec_xg<0>), rg, rb, 0, stream, xg, W_hh0, h1);
        hipLaunchKernelGGL((xg_gemm<1>), gg, gb, 0, stream,
                           (const float*)nullptr, (const float*)nullptr, h1, W_ih1, b_ih1, b_hh1, xg);
        hipLaunchKernelGGL((lstm_rec_xg<1>), rg, rb, 0, stream, xg, W_hh1, out);
    } else {
        // -------- Path B: previous verified fallback --------
        float* h1 = (float*)d_ws;
        dim3 grid(BATCH, 2), block(64);
        hipLaunchKernelGGL((lstm_rec<0>), grid, block, 0, stream,
                           OS, IS, W_ih0, W_hh0, b_ih0, b_hh0, (const float*)nullptr, h1);
        hipLaunchKernelGGL((lstm_rec<1>), grid, block, 0, stream,
                           (const float*)nullptr, (const float*)nullptr,
                           W_ih1, W_hh1, b_ih1, b_hh1, (const float*)h1, out);
    }
}

// Round 2
// 2240.750 us; speedup vs baseline: 1.4749x; 1.4749x over previous
//
#include <hip/hip_runtime.h>

// LSTMencoder: 2-layer biLSTM, B=256, T=2048, H=32 (4H=128 gates), in=32/64.
//
// Adaptive Path A: time-chunked xg precompute.
//   For each layer, for each time-chunk of C steps:
//     xg_gemm_chunk: parallel GEMM producing input-side gate preactivations
//       xg[d][lt][b][128] (biases folded) for both dirs (each dir at its own
//       global time range: fwd t_base+lt, bwd T-1-(t_base+lt)).
//     lstm_rec_chunk: 512 serial chains (one wave each) consuming xg,
//       persisting (h,c) in a 131 KB state slab across chunks.
//   ws layout: [h1 f32 134MB][state 131KB][xg chunk 2*C*B*128*4].
//   C picked at launch = largest in {2048..64} that fits ws_size.
// Fallback Path B: previous harness-verified fused kernel (ws < ~151MB).

#define T_LEN 2048
#define BATCH 256
#define HID   32

__device__ __forceinline__ float frcp(float x) { return __builtin_amdgcn_rcpf(x); }
__device__ __forceinline__ float rdlane(float v, int k) {
    return __int_as_float(__builtin_amdgcn_readlane(__float_as_int(v), k));
}

template<int N>
__device__ __forceinline__ void load_row(float* dst, const float* __restrict__ src) {
#pragma unroll
    for (int i = 0; i < N / 4; ++i) {
        float4 v = reinterpret_cast<const float4*>(src)[i];
        dst[4*i+0] = v.x; dst[4*i+1] = v.y; dst[4*i+2] = v.z; dst[4*i+3] = v.w;
    }
}

// ===================== Path A: chunked xg precompute GEMM =====================
// LAYER 0: x[te][f] = f<16 ? OS[b][te][f] : IS[b][T-1-te][f-16]  (F=32)
// LAYER 1: x[te][f] = h1[te][b][f]                                (F=64)
// writes xg[(((d*C + lt)*B + b)*128 + g] with biases folded in.
template<int LAYER>
__global__ __launch_bounds__(256) void xg_gemm_chunk(
        const float* __restrict__ OS, const float* __restrict__ IS,
        const float* __restrict__ h1,
        const float* __restrict__ Wih, const float* __restrict__ bih,
        const float* __restrict__ bhh, float* __restrict__ xg,
        int t_base, int C)
{
    constexpr int F  = (LAYER == 0) ? 32 : 64;
    constexpr int TT = 16;                      // timesteps per block (per dir)
    __shared__ float xs[2][TT][F];
    const int tid = threadIdx.x;
    const int d   = tid >> 7;                   // 0..1
    const int g   = tid & 127;                  // 0..127
    const int lt0 = blockIdx.x * TT;            // local chunk offset
    const int b   = blockIdx.y;

    // stage x tiles for BOTH dirs into LDS (coalesced in f)
    constexpr int TOT = 2 * TT * F;             // 1024 (L0) / 2048 (L1)
#pragma unroll
    for (int rep = 0; rep < TOT / 256; ++rep) {
        int flat = rep * 256 + tid;
        int d2  = flat / (TT * F);
        int rem = flat % (TT * F);
        int tt  = rem / F, f = rem % F;
        int tl  = t_base + lt0 + tt;
        int te  = d2 ? (T_LEN - 1 - tl) : tl;
        float v;
        if (LAYER == 0) {
            v = (f < 16) ? OS[((size_t)b * T_LEN + te) * 16 + f]
                         : IS[((size_t)b * T_LEN + (T_LEN - 1 - te)) * 16 + (f - 16)];
        } else {
            v = h1[((size_t)te * BATCH + b) * 64 + f];
        }
        xs[d2][tt][f] = v;
    }

    // per-thread weight row (tiny, L2-resident)
    float w[F];
    load_row<F>(w, Wih + ((size_t)d * 128 + g) * F);
    const float bias = bih[d * 128 + g] + bhh[d * 128 + g];
    __syncthreads();

#pragma unroll
    for (int tt = 0; tt < TT; ++tt) {
        float a0 = bias, a1 = 0.f, a2 = 0.f, a3 = 0.f;
#pragma unroll
        for (int j = 0; j < F / 4; ++j) {
            float4 x = reinterpret_cast<const float4*>(xs[d][tt])[j];
            a0 = fmaf(x.x, w[4*j+0], a0);
            a1 = fmaf(x.y, w[4*j+1], a1);
            a2 = fmaf(x.z, w[4*j+2], a2);
            a3 = fmaf(x.w, w[4*j+3], a3);
        }
        xg[(((size_t)d * C + (lt0 + tt)) * BATCH + b) * 128 + g] = (a0 + a1) + (a2 + a3);
    }
}

// ===================== Path A: chunked serial recurrence =====================
// One wave per (b, dir). Lane l owns gates gA=l (i|f), gB=64+l (g|o).
// Consumes xg chunk [d][lt][b][128]; persists h,c in state across chunks.
template<int LAYER>
__global__ __launch_bounds__(64, 1) void lstm_rec_chunk(
        const float* __restrict__ xg, const float* __restrict__ Whh,
        float* __restrict__ outp, float* __restrict__ state,
        int t_base, int C)
{
    const int l   = threadIdx.x;     // 0..63
    const int b   = blockIdx.x;      // 0..255
    const int d   = blockIdx.y;      // 0 fwd, 1 bwd
    const int gA  = l;
    const int gB  = 64 + l;
    const bool lo = (l < HID);
    const int chain = d * BATCH + b;

    float whh_a[HID], whh_b[HID];
    load_row<HID>(whh_a, Whh + ((size_t)d * 128 + gA) * HID);
    load_row<HID>(whh_b, Whh + ((size_t)d * 128 + gB) * HID);

    // restore state (zeros at t_base==0)
    float c = 0.f, hj = 0.f;
    if (t_base > 0 && lo) {
        c  = state[(size_t)chain * 64 + l];
        hj = state[(size_t)chain * 64 + 32 + l];
    }
    float h[HID];                    // wave-uniform (readlane -> SGPR)
#pragma unroll
    for (int k = 0; k < HID; ++k) h[k] = rdlane(hj, k);

    const float* xgd = xg + ((size_t)d * C * BATCH + b) * 128;
    const size_t STRIDE = (size_t)BATCH * 128;

    constexpr int PF = 8;            // prefetch ring (statically indexed)
    float ra[PF], rb[PF];
#pragma unroll
    for (int u = 0; u < PF; ++u) {
        ra[u] = xgd[(size_t)u * STRIDE + gA];
        rb[u] = xgd[(size_t)u * STRIDE + gB];
    }

#pragma unroll 1
    for (int tb = 0; tb < C; tb += PF) {
#pragma unroll
        for (int u = 0; u < PF; ++u) {
            const int lt = tb + u;
            const int tl = t_base + lt;
            const int te = d ? (T_LEN - 1 - tl) : tl;
            const float xa = ra[u], xb = rb[u];
            int tp = lt + PF; if (tp > C - 1) tp = C - 1;   // clamped prefetch
            ra[u] = xgd[(size_t)tp * STRIDE + gA];
            rb[u] = xgd[(size_t)tp * STRIDE + gB];
            // recurrent dot: 8 independent FMA chains of length 8
            float a0 = xa, a1 = 0.f, a2 = 0.f, a3 = 0.f;
            float b0 = xb, b1 = 0.f, b2 = 0.f, b3 = 0.f;
#pragma unroll
            for (int k = 0; k < 8; ++k) {
                a0 = fmaf(h[k],      whh_a[k],      a0);
                a1 = fmaf(h[k + 8],  whh_a[k + 8],  a1);
                a2 = fmaf(h[k + 16], whh_a[k + 16], a2);
                a3 = fmaf(h[k + 24], whh_a[k + 24], a3);
                b0 = fmaf(h[k],      whh_b[k],      b0);
                b1 = fmaf(h[k + 8],  whh_b[k + 8],  b1);
                b2 = fmaf(h[k + 16], whh_b[k + 16], b2);
                b3 = fmaf(h[k + 24], whh_b[k + 24], b3);
            }
            const float accA = (a0 + a1) + (a2 + a3);
            const float accB = (b0 + b1) + (b2 + b3);
            // accA -> sigmoid (i|f); accB -> tanh (g) or sigmoid (o)
            float sA = frcp(1.f + __expf(-accA));
            float argB = lo ? (-2.f * accB) : (-accB);
            float rB = frcp(1.f + __expf(argB));
            float sB = lo ? fmaf(2.f, rB, -1.f) : rB;
            float sf = __shfl(sA, (l + 32) & 63);
            float so = __shfl(sB, (l + 32) & 63);
            c = fmaf(sf, c, sA * sB);
            float tc = fmaf(2.f, frcp(1.f + __expf(-2.f * c)), -1.f);
            hj = so * tc;
            if (lo) {
                if constexpr (LAYER == 0)
                    outp[((size_t)te * BATCH + b) * 64 + d * HID + l] = hj;
                else
                    outp[((size_t)b * T_LEN + te) * 64 + d * HID + l] = hj;
            }
#pragma unroll
            for (int k = 0; k < HID; ++k) h[k] = rdlane(hj, k);
        }
    }

    // save state
    if (lo) {
        state[(size_t)chain * 64 + l]      = c;
        state[(size_t)chain * 64 + 32 + l] = hj;
    }
}

// ===================== Path B: previous verified fused kernel =====================
template<int LAYER>
__global__ __launch_bounds__(64, 1) void lstm_rec(
        const float* __restrict__ OS, const float* __restrict__ IS,
        const float* __restrict__ Wih, const float* __restrict__ Whh,
        const float* __restrict__ bih, const float* __restrict__ bhh,
        const float* __restrict__ h1in, float* __restrict__ outp)
{
    constexpr int F = (LAYER == 0) ? 32 : 64;
    const int l   = threadIdx.x;
    const int b   = blockIdx.x;
    const int dir = blockIdx.y;
    const int gA  = l;
    const int gB  = 64 + l;

    float wih_a[F], wih_b[F], whh_a[HID], whh_b[HID];
    load_row<F>(wih_a, Wih + ((size_t)dir * 128 + gA) * F);
    load_row<F>(wih_b, Wih + ((size_t)dir * 128 + gB) * F);
    load_row<HID>(whh_a, Whh + ((size_t)dir * 128 + gA) * HID);
    load_row<HID>(whh_b, Whh + ((size_t)dir * 128 + gB) * HID);
    const float biasA = bih[dir * 128 + gA] + bhh[dir * 128 + gA];
    const float biasB = bih[dir * 128 + gB] + bhh[dir * 128 + gB];

    float h[HID];
#pragma unroll
    for (int k = 0; k < HID; ++k) h[k] = 0.f;
    float c = 0.f;
    const bool lo = (l < HID);

    float4 X0[F / 4], X1[F / 4];

    auto load_x = [&](float4* X, int tl) {
        const int te = dir ? (T_LEN - 1 - tl) : tl;
        if constexpr (LAYER == 0) {
            const float4* p0 = reinterpret_cast<const float4*>(OS + ((size_t)b * T_LEN + te) * 16);
            const float4* p1 = reinterpret_cast<const float4*>(IS + ((size_t)b * T_LEN + (T_LEN - 1 - te)) * 16);
#pragma unroll
            for (int i = 0; i < 4; ++i) X[i] = p0[i];
#pragma unroll
            for (int i = 0; i < 4; ++i) X[4 + i] = p1[i];
        } else {
            const float4* p = reinterpret_cast<const float4*>(h1in + ((size_t)te * BATCH + b) * 64);
#pragma unroll
            for (int i = 0; i < F / 4; ++i) X[i] = p[i];
        }
    };

    auto step = [&](int tl, const float4* X) {
        const int te = dir ? (T_LEN - 1 - tl) : tl;
        float accA = biasA, accB = biasB;
#pragma unroll
        for (int i = 0; i < F / 4; ++i) {
            accA = fmaf(X[i].x, wih_a[4*i+0], accA);
            accA = fmaf(X[i].y, wih_a[4*i+1], accA);
            accA = fmaf(X[i].z, wih_a[4*i+2], accA);
            accA = fmaf(X[i].w, wih_a[4*i+3], accA);
            accB = fmaf(X[i].x, wih_b[4*i+0], accB);
            accB = fmaf(X[i].y, wih_b[4*i+1], accB);
            accB = fmaf(X[i].z, wih_b[4*i+2], accB);
            accB = fmaf(X[i].w, wih_b[4*i+3], accB);
        }
#pragma unroll
        for (int k = 0; k < HID; ++k) {
            accA = fmaf(h[k], whh_a[k], accA);
            accB = fmaf(h[k], whh_b[k], accB);
        }
        float sA = frcp(1.f + __expf(-accA));
        float argB = lo ? (-2.f * accB) : (-accB);
        float rB = frcp(1.f + __expf(argB));
        float sB = lo ? fmaf(2.f, rB, -1.f) : rB;
        float sf = __shfl(sA, (l + 32) & 63);
        float so = __shfl(sB, (l + 32) & 63);
        c = fmaf(sf, c, sA * sB);
        float tc = fmaf(2.f, frcp(1.f + __expf(-2.f * c)), -1.f);
        float hj = so * tc;
        if (lo) {
            if constexpr (LAYER == 0)
                outp[((size_t)te * BATCH + b) * 64 + dir * HID + l] = hj;
            else
                outp[((size_t)b * T_LEN + te) * 64 + dir * HID + l] = hj;
        }
#pragma unroll
        for (int k = 0; k < HID; ++k) h[k] = rdlane(hj, k);
    };

    load_x(X0, 0);
#pragma unroll 1
    for (int tt = 0; tt < T_LEN; tt += 2) {
        load_x(X1, tt + 1);
        step(tt, X0);
        int nx = tt + 2; if (nx > T_LEN - 1) nx = T_LEN - 1;
        load_x(X0, nx);
        step(tt + 1, X1);
    }
}

extern "C" void kernel_launch(void* const* d_in, const int* in_sizes, int n_in,
                              void* d_out, int out_size, void* d_ws, size_t ws_size,
                              hipStream_t stream) {
    const float* OS    = (const float*)d_in[0];
    const float* IS    = (const float*)d_in[1];
    const float* W_ih0 = (const float*)d_in[2];
    const float* W_hh0 = (const float*)d_in[3];
    const float* b_ih0 = (const float*)d_in[4];
    const float* b_hh0 = (const float*)d_in[5];
    const float* W_ih1 = (const float*)d_in[6];
    const float* W_hh1 = (const float*)d_in[7];
    const float* b_ih1 = (const float*)d_in[8];
    const float* b_hh1 = (const float*)d_in[9];
    float* out = (float*)d_out;

    const size_t H1_BYTES = (size_t)T_LEN * BATCH * 64 * sizeof(float);   // 134,217,728
    const size_t ST_BYTES = (size_t)512 * 64 * sizeof(float);             // 131,072

    // pick largest chunk C (= T/NC) whose xg buffer fits the remaining ws
    int C = 0;
    if (ws_size > H1_BYTES + ST_BYTES) {
        size_t avail = ws_size - H1_BYTES - ST_BYTES;
        for (int nc = 1; nc <= 32; nc <<= 1) {
            size_t xg_bytes = (size_t)2 * (T_LEN / nc) * BATCH * 128 * sizeof(float);
            if (xg_bytes <= avail) { C = T_LEN / nc; break; }
        }
    }

    if (C >= 64) {
        // -------- Path A: chunked --------
        float* h1 = (float*)d_ws;
        float* st = (float*)((char*)d_ws + H1_BYTES);
        float* xg = (float*)((char*)d_ws + H1_BYTES + ST_BYTES);
        dim3 gb(256), rb(64), rg(BATCH, 2);
        for (int t_base = 0; t_base < T_LEN; t_base += C) {
            dim3 gg(C / 16, BATCH);
            hipLaunchKernelGGL((xg_gemm_chunk<0>), gg, gb, 0, stream,
                               OS, IS, (const float*)nullptr, W_ih0, b_ih0, b_hh0, xg, t_base, C);
            hipLaunchKernelGGL((lstm_rec_chunk<0>), rg, rb, 0, stream,
                               xg, W_hh0, h1, st, t_base, C);
        }
        for (int t_base = 0; t_base < T_LEN; t_base += C) {
            dim3 gg(C / 16, BATCH);
            hipLaunchKernelGGL((xg_gemm_chunk<1>), gg, gb, 0, stream,
                               (const float*)nullptr, (const float*)nullptr, h1,
                               W_ih1, b_ih1, b_hh1, xg, t_base, C);
            hipLaunchKernelGGL((lstm_rec_chunk<1>), rg, rb, 0, stream,
                               xg, W_hh1, out, st, t_base, C);
        }
    } else {
        // -------- Path B: previous verified fallback --------
        float* h1 = (float*)d_ws;
        dim3 grid(BATCH, 2), block(64);
        hipLaunchKernelGGL((lstm_rec<0>), grid, block, 0, stream,
                           OS, IS, W_ih0, W_hh0, b_ih0, b_hh0, (const float*)nullptr, h1);
        hipLaunchKernelGGL((lstm_rec<1>), grid, block, 0, stream,
                           (const float*)nullptr, (const float*)nullptr,
                           W_ih1, W_hh1, b_ih1, b_hh1, (const float*)h1, out);
    }
}